// Round 1
// baseline (441.401 us; speedup 1.0000x reference)
//
#include <hip/hip_runtime.h>

#define SEQ 4096
#define DM 1024
#define NH 16
#define HD 64

typedef __attribute__((ext_vector_type(8))) short short8;
typedef __attribute__((ext_vector_type(4))) short short4v;
typedef __attribute__((ext_vector_type(4))) float float4v;

__device__ __forceinline__ short f2bf(float f) {
    union { float f; unsigned u; } v; v.f = f;
    unsigned u = v.u;
    return (short)((u + 0x7fffu + ((u >> 16) & 1u)) >> 16);
}

// ---------------- cast x (fp32 -> bf16), vectorized ----------------
__global__ void cast_x(const float* __restrict__ in, short* __restrict__ out, int n4) {
    int i = blockIdx.x * blockDim.x + threadIdx.x;
    if (i < n4) {
        float4v x = ((const float4v*)in)[i];
        short4v o;
        o[0] = f2bf(x[0]); o[1] = f2bf(x[1]); o[2] = f2bf(x[2]); o[3] = f2bf(x[3]);
        ((short4v*)out)[i] = o;
    }
}

// ------------- transpose + cast: fp32 [H][W] -> bf16 [W][H] -------------
__global__ void transpose_cast(const float* __restrict__ in, short* __restrict__ out,
                               int H, int W) {
    __shared__ float tile[32][33];
    int bx = blockIdx.x * 32, by = blockIdx.y * 32;
    int tx = threadIdx.x, ty = threadIdx.y;   // 32 x 8
#pragma unroll
    for (int i = 0; i < 32; i += 8)
        tile[ty + i][tx] = in[(by + ty + i) * W + bx + tx];
    __syncthreads();
#pragma unroll
    for (int i = 0; i < 32; i += 8)
        out[(bx + ty + i) * H + by + tx] = f2bf(tile[tx][ty + i]);
}

// ------------- V transpose: qkv bf16 [l][2048+h*64+d] -> vt [h][d][l] -------------
__global__ void transpose_v(const short* __restrict__ qkv, short* __restrict__ vt) {
    __shared__ short tile[32][33];
    int h = blockIdx.z;
    int l0 = blockIdx.x * 32;
    int d0 = blockIdx.y * 32;
    int tx = threadIdx.x, ty = threadIdx.y;
#pragma unroll
    for (int i = 0; i < 32; i += 8)
        tile[ty + i][tx] = qkv[(l0 + ty + i) * (3 * DM) + 2 * DM + h * HD + d0 + tx];
    __syncthreads();
#pragma unroll
    for (int i = 0; i < 32; i += 8)
        vt[(h * HD + d0 + ty + i) * SEQ + l0 + tx] = tile[tx][ty + i];
}

// ------------- GEMM: A[M,K] bf16 x BT[N,K] bf16 -> C[M,N] (fp32 or bf16) -------------
// 128x128 block tile, BK=32, 4 waves (2x2), each wave 64x64 via 4x4 MFMA 16x16x32.
template <typename OutT>
__global__ __launch_bounds__(256) void gemm_bt(const short* __restrict__ A,
                                               const short* __restrict__ BT,
                                               OutT* __restrict__ C,
                                               int M, int N, int K) {
    constexpr int LS = 40;  // 128-row LDS stride (+8 pad: 80B rows, 16B aligned, 2-way-free banks)
    __shared__ short As[128 * LS];
    __shared__ short Bs[128 * LS];
    int tid  = threadIdx.x;
    int m0   = blockIdx.y * 128;
    int n0   = blockIdx.x * 128;
    int w    = tid >> 6, lane = tid & 63;
    int wm   = w >> 1,  wn   = w & 1;
    int quad = lane >> 4, l15 = lane & 15;

    float4v acc[4][4];
#pragma unroll
    for (int mi = 0; mi < 4; mi++)
#pragma unroll
        for (int ni = 0; ni < 4; ni++)
            acc[mi][ni] = {0.f, 0.f, 0.f, 0.f};

    for (int k0 = 0; k0 < K; k0 += 32) {
        __syncthreads();
#pragma unroll
        for (int t = 0; t < 2; t++) {
            int c = tid + t * 256;       // 512 x 16B chunks each for A and B
            int r = c >> 2, q = c & 3;
            *(short8*)&As[r * LS + q * 8] = *(const short8*)&A[(m0 + r) * K + k0 + q * 8];
            *(short8*)&Bs[r * LS + q * 8] = *(const short8*)&BT[(n0 + r) * K + k0 + q * 8];
        }
        __syncthreads();
        short8 a[4], b[4];
#pragma unroll
        for (int mi = 0; mi < 4; mi++)
            a[mi] = *(const short8*)&As[(wm * 64 + mi * 16 + l15) * LS + quad * 8];
#pragma unroll
        for (int ni = 0; ni < 4; ni++)
            b[ni] = *(const short8*)&Bs[(wn * 64 + ni * 16 + l15) * LS + quad * 8];
#pragma unroll
        for (int mi = 0; mi < 4; mi++)
#pragma unroll
            for (int ni = 0; ni < 4; ni++)
                acc[mi][ni] = __builtin_amdgcn_mfma_f32_16x16x32_bf16(a[mi], b[ni], acc[mi][ni], 0, 0, 0);
    }

#pragma unroll
    for (int mi = 0; mi < 4; mi++)
#pragma unroll
        for (int ni = 0; ni < 4; ni++)
#pragma unroll
            for (int r = 0; r < 4; r++) {
                int row = m0 + wm * 64 + mi * 16 + quad * 4 + r;
                int col = n0 + wn * 64 + ni * 16 + l15;
                float v = acc[mi][ni][r];
                if constexpr (sizeof(OutT) == 2) C[row * N + col] = (OutT)f2bf(v);
                else                             C[row * N + col] = (OutT)v;
            }
}

// ------------- flash attention, causal, bf16 MFMA -------------
// block: 256 thr = 4 waves; block covers 128 q rows, wave owns 32 (2 m-tiles of 16).
// KV tiles of 64. Wave-private state -> no barriers; per-wave causal early exit.
__global__ __launch_bounds__(256) void attn_kernel(const short* __restrict__ qkv,
                                                   const short* __restrict__ vt,
                                                   short* __restrict__ aout) {
    __shared__ short P[4][32 * 72];  // per-wave P tile, stride 72 (144B rows, 2-way-free)
    int h  = blockIdx.y;
    int q0 = (gridDim.x - 1 - blockIdx.x) * 128;  // heavy (high-q) blocks launch first
    int tid = threadIdx.x;
    int w = tid >> 6, lane = tid & 63;
    int quad = lane >> 4, l15 = lane & 15;
    int qw = q0 + w * 32;

    const float SC = 0.125f * 1.44269504088896f;  // scale * log2(e); all softmax in exp2 domain

    // Q fragments (A-layout: m=l15, k=quad*8+j), rows qw+mi*16+l15, d = kk*32..
    short8 aq[2][2];
#pragma unroll
    for (int mi = 0; mi < 2; mi++)
#pragma unroll
        for (int kk = 0; kk < 2; kk++)
            aq[mi][kk] = *(const short8*)&qkv[(qw + mi * 16 + l15) * (3 * DM) + h * HD + kk * 32 + quad * 8];

    float m_s[2][4], l_s[2][4];
    float4v o[2][4];
#pragma unroll
    for (int mi = 0; mi < 2; mi++)
#pragma unroll
        for (int r = 0; r < 4; r++) {
            m_s[mi][r] = -3e38f;
            l_s[mi][r] = 0.f;
        }
#pragma unroll
    for (int mi = 0; mi < 2; mi++)
#pragma unroll
        for (int dt = 0; dt < 4; dt++)
            o[mi][dt] = {0.f, 0.f, 0.f, 0.f};

    short* Pw = P[w];
    int s_last = qw + 31;

    for (int s0 = 0; s0 <= s_last; s0 += 64) {
        // S = Q K^T  (B-frag: n = kv col = l15, k = d contiguous)
        float4v s[2][4];
#pragma unroll
        for (int mi = 0; mi < 2; mi++)
#pragma unroll
            for (int ni = 0; ni < 4; ni++) {
                float4v a = {0.f, 0.f, 0.f, 0.f};
#pragma unroll
                for (int kk = 0; kk < 2; kk++) {
                    short8 bk = *(const short8*)&qkv[(s0 + ni * 16 + l15) * (3 * DM) + DM + h * HD + kk * 32 + quad * 8];
                    a = __builtin_amdgcn_mfma_f32_16x16x32_bf16(aq[mi][kk], bk, a, 0, 0, 0);
                }
                s[mi][ni] = a;
            }
        // online softmax (C-layout rows: quad*4+r)
#pragma unroll
        for (int mi = 0; mi < 2; mi++) {
            float rmax[4], rsum[4];
#pragma unroll
            for (int r = 0; r < 4; r++) {
                int row = qw + mi * 16 + quad * 4 + r;
                float mx = -3e38f;
#pragma unroll
                for (int ni = 0; ni < 4; ni++) {
                    int col = s0 + ni * 16 + l15;
                    float v = s[mi][ni][r] * SC;
                    v = (col <= row) ? v : -3e38f;
                    s[mi][ni][r] = v;
                    mx = fmaxf(mx, v);
                }
                rmax[r] = mx;
            }
#pragma unroll
            for (int off = 1; off < 16; off <<= 1)
#pragma unroll
                for (int r = 0; r < 4; r++)
                    rmax[r] = fmaxf(rmax[r], __shfl_xor(rmax[r], off, 64));
#pragma unroll
            for (int r = 0; r < 4; r++) {
                float mnew  = fmaxf(m_s[mi][r], rmax[r]);
                float alpha = exp2f(m_s[mi][r] - mnew);
                m_s[mi][r] = mnew;
                l_s[mi][r] *= alpha;
#pragma unroll
                for (int dt = 0; dt < 4; dt++)
                    o[mi][dt][r] *= alpha;
                float sum = 0.f;
#pragma unroll
                for (int ni = 0; ni < 4; ni++) {
                    float p = exp2f(s[mi][ni][r] - mnew);
                    s[mi][ni][r] = p;
                    sum += p;
                }
                rsum[r] = sum;
            }
#pragma unroll
            for (int off = 1; off < 16; off <<= 1)
#pragma unroll
                for (int r = 0; r < 4; r++)
                    rsum[r] += __shfl_xor(rsum[r], off, 64);
#pragma unroll
            for (int r = 0; r < 4; r++)
                l_s[mi][r] += rsum[r];
            // P -> LDS (C-layout write)
#pragma unroll
            for (int ni = 0; ni < 4; ni++)
#pragma unroll
                for (int r = 0; r < 4; r++)
                    Pw[(mi * 16 + quad * 4 + r) * 72 + ni * 16 + l15] = f2bf(s[mi][ni][r]);
        }
        // O += P V   (A-frag of P from LDS; B-frag from vt, k=s contiguous)
#pragma unroll
        for (int mi = 0; mi < 2; mi++) {
            short8 pa[2];
#pragma unroll
            for (int kk = 0; kk < 2; kk++)
                pa[kk] = *(const short8*)&Pw[(mi * 16 + l15) * 72 + kk * 32 + quad * 8];
#pragma unroll
            for (int dt = 0; dt < 4; dt++)
#pragma unroll
                for (int kk = 0; kk < 2; kk++) {
                    short8 bv = *(const short8*)&vt[(h * HD + dt * 16 + l15) * SEQ + s0 + kk * 32 + quad * 8];
                    o[mi][dt] = __builtin_amdgcn_mfma_f32_16x16x32_bf16(pa[kk], bv, o[mi][dt], 0, 0, 0);
                }
        }
    }
    // epilogue: O / l -> aout [l][h*64+d] bf16
#pragma unroll
    for (int mi = 0; mi < 2; mi++)
#pragma unroll
        for (int r = 0; r < 4; r++) {
            float inv = 1.0f / l_s[mi][r];
#pragma unroll
            for (int dt = 0; dt < 4; dt++) {
                float v = o[mi][dt][r] * inv;
                aout[(qw + mi * 16 + quad * 4 + r) * DM + h * HD + dt * 16 + l15] = f2bf(v);
            }
        }
}

extern "C" void kernel_launch(void* const* d_in, const int* in_sizes, int n_in,
                              void* d_out, int out_size, void* d_ws, size_t ws_size,
                              hipStream_t stream) {
    const float* x    = (const float*)d_in[0];
    const float* Wqkv = (const float*)d_in[1];
    const float* Wout = (const float*)d_in[2];
    float* out = (float*)d_out;

    char* ws = (char*)d_ws;
    // workspace layout (all 16B aligned)
    short* xb    = (short*)(ws);                               // 4096x1024 bf16   (8 MB)
    short* wqkvT = (short*)(ws + 8388608);                     // 3072x1024 bf16   (6 MB)
    short* woutT = (short*)(ws + 8388608 + 6291456);           // 1024x1024 bf16   (2 MB)
    short* qkv   = (short*)(ws + 16777216);                    // 4096x3072 bf16   (24 MB)
    short* vt    = (short*)(ws + 16777216 + 25165824);         // 16x64x4096 bf16  (8 MB)
    short* ao    = (short*)(ws + 16777216 + 25165824 + 8388608); // 4096x1024 bf16 (8 MB)

    cast_x<<<4096, 256, 0, stream>>>(x, xb, (SEQ * DM) / 4);
    transpose_cast<<<dim3(3 * DM / 32, DM / 32), dim3(32, 8), 0, stream>>>(Wqkv, wqkvT, DM, 3 * DM);
    transpose_cast<<<dim3(DM / 32, DM / 32), dim3(32, 8), 0, stream>>>(Wout, woutT, DM, DM);

    gemm_bt<short><<<dim3(3 * DM / 128, SEQ / 128), 256, 0, stream>>>(xb, wqkvT, qkv, SEQ, 3 * DM, DM);

    transpose_v<<<dim3(SEQ / 32, HD / 32, NH), dim3(32, 8), 0, stream>>>(qkv, vt);

    attn_kernel<<<dim3(SEQ / 128, NH), 256, 0, stream>>>(qkv, vt, ao);

    gemm_bt<float><<<dim3(DM / 128, SEQ / 128), 256, 0, stream>>>(ao, woutT, out, SEQ, DM, DM);
}

// Round 2
// 267.160 us; speedup vs baseline: 1.6522x; 1.6522x over previous
//
#include <hip/hip_runtime.h>

#define SEQ 4096
#define DM 1024
#define NH 16
#define HD 64

typedef __attribute__((ext_vector_type(8))) short short8;
typedef __attribute__((ext_vector_type(4))) short short4v;
typedef __attribute__((ext_vector_type(4))) float float4v;

__device__ __forceinline__ short f2bf(float f) {
    union { float f; unsigned u; } v; v.f = f;
    unsigned u = v.u;
    return (short)((u + 0x7fffu + ((u >> 16) & 1u)) >> 16);
}
// round-half-up bf16 (2 ops); used for P where 0.2% bias is irrelevant
__device__ __forceinline__ short f2bf_fast(float f) {
    union { float f; unsigned u; } v; v.f = f;
    return (short)((v.u + 0x8000u) >> 16);
}

__device__ __forceinline__ void gload_lds16(const void* g, void* l) {
    __builtin_amdgcn_global_load_lds(
        (const __attribute__((address_space(1))) void*)g,
        (__attribute__((address_space(3))) void*)l, 16, 0, 0);
}

// ---------------- cast x (fp32 -> bf16), vectorized ----------------
__global__ void cast_x(const float* __restrict__ in, short* __restrict__ out, int n4) {
    int i = blockIdx.x * blockDim.x + threadIdx.x;
    if (i < n4) {
        float4v x = ((const float4v*)in)[i];
        short4v o;
        o[0] = f2bf(x[0]); o[1] = f2bf(x[1]); o[2] = f2bf(x[2]); o[3] = f2bf(x[3]);
        ((short4v*)out)[i] = o;
    }
}

// ------ transpose + cast: fp32 [H][W] -> bf16 [W][H]; rows < scaled_rows get *scale ------
__global__ void transpose_cast(const float* __restrict__ in, short* __restrict__ out,
                               int H, int W, int scaled_rows, float scale) {
    __shared__ float tile[32][33];
    int bx = blockIdx.x * 32, by = blockIdx.y * 32;
    int tx = threadIdx.x, ty = threadIdx.y;   // 32 x 8
#pragma unroll
    for (int i = 0; i < 32; i += 8)
        tile[ty + i][tx] = in[(by + ty + i) * W + bx + tx];
    __syncthreads();
#pragma unroll
    for (int i = 0; i < 32; i += 8) {
        int orow = bx + ty + i;
        float sc = (orow < scaled_rows) ? scale : 1.0f;
        out[orow * H + by + tx] = f2bf(tile[tx][ty + i] * sc);
    }
}

// ------------- V transpose: qkv bf16 [l][2048+h*64+d] -> vt [h][d][l] -------------
__global__ void transpose_v(const short* __restrict__ qkv, short* __restrict__ vt) {
    __shared__ short tile[32][33];
    int h = blockIdx.z;
    int l0 = blockIdx.x * 32;
    int d0 = blockIdx.y * 32;
    int tx = threadIdx.x, ty = threadIdx.y;
#pragma unroll
    for (int i = 0; i < 32; i += 8)
        tile[ty + i][tx] = qkv[(l0 + ty + i) * (3 * DM) + 2 * DM + h * HD + d0 + tx];
    __syncthreads();
#pragma unroll
    for (int i = 0; i < 32; i += 8)
        vt[(h * HD + d0 + ty + i) * SEQ + l0 + tx] = tile[tx][ty + i];
}

// ------------- GEMM: A[M,K] bf16 x BT[N,K] bf16 -> C[M,N] -------------
// m97 structure: 128x128 tile, BK=32, global_load_lds width=16 staging (unpadded 64B rows).
template <typename OutT>
__global__ __launch_bounds__(256) void gemm_bt(const short* __restrict__ A,
                                               const short* __restrict__ BT,
                                               OutT* __restrict__ C,
                                               int M, int N, int K) {
    __shared__ short As[128 * 32];
    __shared__ short Bs[128 * 32];
    int tid  = threadIdx.x;
    int m0   = blockIdx.y * 128;
    int n0   = blockIdx.x * 128;
    int w    = tid >> 6, lane = tid & 63;
    int wm   = w >> 1,  wn   = w & 1;
    int quad = lane >> 4, l15 = lane & 15;
    int srow = lane >> 2;           // row within 16-row chunk
    int scol = (lane & 3) * 8;      // k-offset in shorts

    float4v acc[4][4];
#pragma unroll
    for (int mi = 0; mi < 4; mi++)
#pragma unroll
        for (int ni = 0; ni < 4; ni++)
            acc[mi][ni] = {0.f, 0.f, 0.f, 0.f};

    for (int k0 = 0; k0 < K; k0 += 32) {
        __syncthreads();
#pragma unroll
        for (int t = 0; t < 2; t++) {
            int chunk = w * 2 + t;            // 0..7, 16 rows each
            int r = chunk * 16 + srow;
            gload_lds16(&A[(m0 + r) * K + k0 + scol], &As[chunk * 16 * 32]);
            gload_lds16(&BT[(n0 + r) * K + k0 + scol], &Bs[chunk * 16 * 32]);
        }
        __syncthreads();
        short8 a[4], b[4];
#pragma unroll
        for (int mi = 0; mi < 4; mi++)
            a[mi] = *(const short8*)&As[(wm * 64 + mi * 16 + l15) * 32 + quad * 8];
#pragma unroll
        for (int ni = 0; ni < 4; ni++)
            b[ni] = *(const short8*)&Bs[(wn * 64 + ni * 16 + l15) * 32 + quad * 8];
#pragma unroll
        for (int mi = 0; mi < 4; mi++)
#pragma unroll
            for (int ni = 0; ni < 4; ni++)
                acc[mi][ni] = __builtin_amdgcn_mfma_f32_16x16x32_bf16(a[mi], b[ni], acc[mi][ni], 0, 0, 0);
    }

#pragma unroll
    for (int mi = 0; mi < 4; mi++)
#pragma unroll
        for (int ni = 0; ni < 4; ni++)
#pragma unroll
            for (int r = 0; r < 4; r++) {
                int row = m0 + wm * 64 + mi * 16 + quad * 4 + r;
                int col = n0 + wn * 64 + ni * 16 + l15;
                float v = acc[mi][ni][r];
                if constexpr (sizeof(OutT) == 2) C[row * N + col] = (OutT)f2bf(v);
                else                             C[row * N + col] = (OutT)v;
            }
}

// ------------- flash attention, causal, bf16 MFMA -------------
// Fixed-max softmax (Q pre-scaled by 0.125*log2e): P = exp2(S), l deferred to epilogue.
// K/V software-pipelined; CU-pairing block remap for causal balance.
__global__ __launch_bounds__(256, 2) void attn_kernel(const short* __restrict__ qkv,
                                                      const short* __restrict__ vtp,
                                                      short* __restrict__ aout) {
    __shared__ short P[4][32 * 72];  // per-wave P tile, stride 72 shorts
    int x = blockIdx.x;              // 0..31
    int h = blockIdx.y;              // 0..15
    // blocks l and l+256 co-reside on a CU; make their q-weights complementary
    int t = (h < 8) ? (31 - x) : x;
    int q0 = t * 128;
    int tid = threadIdx.x;
    int w = tid >> 6, lane = tid & 63;
    int quad = lane >> 4, l15 = lane & 15;
    int qw = q0 + w * 32;

    const short* Kbase = qkv + DM + h * HD;       // + row*3072 + koff
    const short* Vbase = vtp + (h * HD) * SEQ;    // + (dt*16+l15)*SEQ + s + koff

    // Q fragments (A-layout: m=l15, k=quad*8+j); Q is pre-scaled
    short8 aq[2][2];
#pragma unroll
    for (int mi = 0; mi < 2; mi++)
#pragma unroll
        for (int kk = 0; kk < 2; kk++)
            aq[mi][kk] = *(const short8*)&qkv[(qw + mi * 16 + l15) * (3 * DM) + h * HD + kk * 32 + quad * 8];

    float lp[2][4];
    float4v o[2][4];
#pragma unroll
    for (int mi = 0; mi < 2; mi++)
#pragma unroll
        for (int r = 0; r < 4; r++)
            lp[mi][r] = 0.f;
#pragma unroll
    for (int mi = 0; mi < 2; mi++)
#pragma unroll
        for (int dt = 0; dt < 4; dt++)
            o[mi][dt] = {0.f, 0.f, 0.f, 0.f};

    short* Pw = P[w];
    int nT = (qw + 31) / 64 + 1;

    short8 kc[8], vc[8];
#pragma unroll
    for (int ni = 0; ni < 4; ni++)
#pragma unroll
        for (int kk = 0; kk < 2; kk++)
            kc[ni * 2 + kk] = *(const short8*)&Kbase[(ni * 16 + l15) * (3 * DM) + kk * 32 + quad * 8];
#pragma unroll
    for (int dt = 0; dt < 4; dt++)
#pragma unroll
        for (int kk = 0; kk < 2; kk++)
            vc[dt * 2 + kk] = *(const short8*)&Vbase[(dt * 16 + l15) * SEQ + kk * 32 + quad * 8];

    for (int tt = 0; tt < nT; tt++) {
        int s0 = tt * 64;
        int sn = (tt + 1 < nT) ? s0 + 64 : s0;   // clamped prefetch target

        // S = Q K^T
        float4v s[2][4];
#pragma unroll
        for (int mi = 0; mi < 2; mi++)
#pragma unroll
            for (int ni = 0; ni < 4; ni++) {
                float4v a = {0.f, 0.f, 0.f, 0.f};
#pragma unroll
                for (int kk = 0; kk < 2; kk++)
                    a = __builtin_amdgcn_mfma_f32_16x16x32_bf16(aq[mi][kk], kc[ni * 2 + kk], a, 0, 0, 0);
                s[mi][ni] = a;
            }
        // prefetch K(t+1) (kc fully consumed above)
#pragma unroll
        for (int ni = 0; ni < 4; ni++)
#pragma unroll
            for (int kk = 0; kk < 2; kk++)
                kc[ni * 2 + kk] = *(const short8*)&Kbase[(sn + ni * 16 + l15) * (3 * DM) + kk * 32 + quad * 8];

        // causal mask only on diagonal tiles (wave-uniform branch)
        if (s0 + 63 > qw) {
#pragma unroll
            for (int mi = 0; mi < 2; mi++)
#pragma unroll
                for (int ni = 0; ni < 4; ni++)
#pragma unroll
                    for (int r = 0; r < 4; r++) {
                        int col = s0 + ni * 16 + l15;
                        int row = qw + mi * 16 + quad * 4 + r;
                        if (col > row) s[mi][ni][r] = -__builtin_inff();
                    }
        }
        // P = exp2(S); accumulate per-lane row partial of l; write P to LDS (C-layout)
#pragma unroll
        for (int mi = 0; mi < 2; mi++)
#pragma unroll
            for (int ni = 0; ni < 4; ni++)
#pragma unroll
                for (int r = 0; r < 4; r++) {
                    float p = exp2f(s[mi][ni][r]);
                    lp[mi][r] += p;
                    Pw[(mi * 16 + quad * 4 + r) * 72 + ni * 16 + l15] = f2bf_fast(p);
                }
        // O += P V
#pragma unroll
        for (int mi = 0; mi < 2; mi++) {
            short8 pa[2];
#pragma unroll
            for (int kk = 0; kk < 2; kk++)
                pa[kk] = *(const short8*)&Pw[(mi * 16 + l15) * 72 + kk * 32 + quad * 8];
#pragma unroll
            for (int dt = 0; dt < 4; dt++)
#pragma unroll
                for (int kk = 0; kk < 2; kk++)
                    o[mi][dt] = __builtin_amdgcn_mfma_f32_16x16x32_bf16(pa[kk], vc[dt * 2 + kk], o[mi][dt], 0, 0, 0);
        }
        // prefetch V(t+1) (vc fully consumed above)
#pragma unroll
        for (int dt = 0; dt < 4; dt++)
#pragma unroll
            for (int kk = 0; kk < 2; kk++)
                vc[dt * 2 + kk] = *(const short8*)&Vbase[(dt * 16 + l15) * SEQ + sn + kk * 32 + quad * 8];
    }

    // epilogue: reduce l across the 16 column-lanes (lands on rows quad*4+r), then O/l
#pragma unroll
    for (int mi = 0; mi < 2; mi++)
#pragma unroll
        for (int r = 0; r < 4; r++) {
#pragma unroll
            for (int off = 1; off < 16; off <<= 1)
                lp[mi][r] += __shfl_xor(lp[mi][r], off, 64);
        }
#pragma unroll
    for (int mi = 0; mi < 2; mi++)
#pragma unroll
        for (int r = 0; r < 4; r++) {
            float inv = 1.0f / lp[mi][r];
#pragma unroll
            for (int dt = 0; dt < 4; dt++) {
                float v = o[mi][dt][r] * inv;
                aout[(qw + mi * 16 + quad * 4 + r) * DM + h * HD + dt * 16 + l15] = f2bf(v);
            }
        }
}

extern "C" void kernel_launch(void* const* d_in, const int* in_sizes, int n_in,
                              void* d_out, int out_size, void* d_ws, size_t ws_size,
                              hipStream_t stream) {
    const float* x    = (const float*)d_in[0];
    const float* Wqkv = (const float*)d_in[1];
    const float* Wout = (const float*)d_in[2];
    float* out = (float*)d_out;

    char* ws = (char*)d_ws;
    short* xb    = (short*)(ws);                                 // 4096x1024 bf16   (8 MB)
    short* wqkvT = (short*)(ws + 8388608);                       // 3072x1024 bf16   (6 MB)
    short* woutT = (short*)(ws + 8388608 + 6291456);             // 1024x1024 bf16   (2 MB)
    short* qkv   = (short*)(ws + 16777216);                      // 4096x3072 bf16   (24 MB)
    short* vt    = (short*)(ws + 16777216 + 25165824);           // 16x64x4096 bf16  (8 MB)
    short* ao    = (short*)(ws + 16777216 + 25165824 + 8388608); // 4096x1024 bf16   (8 MB)

    const float SC = 0.18033688011112042f;  // (1/sqrt(64)) * log2(e)

    cast_x<<<4096, 256, 0, stream>>>(x, xb, (SEQ * DM) / 4);
    // scale Q columns (rows 0..1023 of the transposed weight) by SC -> softmax in exp2 domain
    transpose_cast<<<dim3(3 * DM / 32, DM / 32), dim3(32, 8), 0, stream>>>(Wqkv, wqkvT, DM, 3 * DM, DM, SC);
    transpose_cast<<<dim3(DM / 32, DM / 32), dim3(32, 8), 0, stream>>>(Wout, woutT, DM, DM, 0, 1.0f);

    gemm_bt<short><<<dim3(3 * DM / 128, SEQ / 128), 256, 0, stream>>>(xb, wqkvT, qkv, SEQ, 3 * DM, DM);

    transpose_v<<<dim3(SEQ / 32, HD / 32, NH), dim3(32, 8), 0, stream>>>(qkv, vt);

    attn_kernel<<<dim3(SEQ / 128, NH), 256, 0, stream>>>(qkv, vt, ao);

    gemm_bt<float><<<dim3(DM / 128, SEQ / 128), 256, 0, stream>>>(ao, woutT, out, SEQ, DM, DM);
}